// Round 6
// baseline (4916.089 us; speedup 1.0000x reference)
//
#include <hip/hip_runtime.h>
#include <hip/hip_bf16.h>

#define B_ 256
#define S_ 2048
#define D_ 16
#define H_ 128
#define NT 768
#define NA 256

typedef unsigned int u32;
typedef unsigned short u16;
typedef _Float16 h2t __attribute__((ext_vector_type(2)));

// ---- output layout (flat f32): returns | volatility | hidden_h | hidden_c
#define RET0 ((size_t)0)
#define VOL0 ((size_t)524288)
#define HH0  ((size_t)1048576)
#define HC0  ((size_t)1114112)

__device__ __forceinline__ float fdot2(u32 a, u32 b, float c) {
    return __builtin_amdgcn_fdot2(__builtin_bit_cast(h2t, a),
                                  __builtin_bit_cast(h2t, b), c, false);
}
__device__ __forceinline__ u32 packh2(float a, float b) {
    h2t h; h[0] = (_Float16)a; h[1] = (_Float16)b;
    return __builtin_bit_cast(u32, h);
}
__device__ __forceinline__ float sigm(float x) {
    return __builtin_amdgcn_rcpf(1.f + __builtin_amdgcn_exp2f(-1.44269504f * x));
}
__device__ __forceinline__ float tanh_(float x) {
    return 2.f * __builtin_amdgcn_rcpf(1.f + __builtin_amdgcn_exp2f(-2.88539008f * x)) - 1.f;
}
__device__ __forceinline__ float softplus_(float x) {
    if (x > 20.f) return x;
    const float e = __builtin_amdgcn_exp2f(1.44269504f * x);
    return 0.69314718f * __builtin_amdgcn_logf(1.f + e);  // v_log_f32 is log2
}

// A-side (layer 0): gate stride 36 within w[144]
#define GD4(v, i)                                                              \
    a0 = fdot2(v, w[i], a0);       a1 = fdot2(v, w[36 + (i)], a1);             \
    a2 = fdot2(v, w[72 + (i)], a2); a3 = fdot2(v, w[108 + (i)], a3);
// B-side (layer 1): gate stride 32 within w[128]
#define GD32(v, i)                                                             \
    a0 = fdot2(v, w[i], a0);       a1 = fdot2(v, w[32 + (i)], a1);             \
    a2 = fdot2(v, w[64 + (i)], a2); a3 = fdot2(v, w[96 + (i)], a3);

__global__ __launch_bounds__(NT, 3) void mtl_fused(
    const float* __restrict__ x,
    const float* __restrict__ Wih0, const float* __restrict__ Whh0,
    const float* __restrict__ bih0, const float* __restrict__ bhh0,
    const float* __restrict__ Wih1, const float* __restrict__ Whh1,
    const float* __restrict__ bih1, const float* __restrict__ bhh1,
    const float* __restrict__ Wr1, const float* __restrict__ br1,
    const float* __restrict__ Wr2, const float* __restrict__ br2,
    const float* __restrict__ Wv1, const float* __restrict__ bv1,
    const float* __restrict__ Wv2, const float* __restrict__ bv2,
    float* __restrict__ out)
{
    __shared__ u32 xp2[2][4096];      // 512-step x window, f16 pairs (32KB)
    __shared__ u32 h1b[2][64];        // h1 state double buffer (f16 pairs)
    __shared__ u32 h2b[2][64];        // h2 state double buffer
    __shared__ float redbuf[2][8];    // per-B-wave head partials (lag 1)
    __shared__ float rvr[S_];         // returns, f32, full sequence (8KB)
    __shared__ float rvv[S_];         // volatility, f32, full sequence (8KB)

    const int tid = threadIdx.x;
    const int b = blockIdx.x;
    const bool isA = (tid < NA);
    const int ma = tid >> 1, k0 = tid & 1;             // A: unit, k-half
    const int tb = tid - NA, mb = tb >> 2, q = tb & 3; // B: unit, k-quarter

    u32 w[144];
    float bias[4];
    float hb1 = 0.f, hw2 = 0.f;
    const float br2f = br2[0], bv2f = bv2[0];

    if (isA) {
#pragma unroll
        for (int g = 0; g < 4; ++g) {
            const int row = g * H_ + ma;
            const float4* wxr = (const float4*)(Wih0 + row * D_ + k0 * 8);
#pragma unroll
            for (int j4 = 0; j4 < 2; ++j4) {
                const float4 f = wxr[j4];
                w[g * 36 + j4 * 2]     = packh2(f.x, f.y);
                w[g * 36 + j4 * 2 + 1] = packh2(f.z, f.w);
            }
            const float4* whr = (const float4*)(Whh0 + row * H_ + k0 * 64);
#pragma unroll
            for (int j4 = 0; j4 < 16; ++j4) {
                const float4 f = whr[j4];
                w[g * 36 + 4 + j4 * 2] = packh2(f.x, f.y);
                w[g * 36 + 5 + j4 * 2] = packh2(f.z, f.w);
            }
            bias[g] = bih0[row] + bhh0[row];
        }
    } else {
#pragma unroll
        for (int g = 0; g < 4; ++g) {
            const int row = g * H_ + mb;
            const float4* wir = (const float4*)(Wih1 + row * H_ + q * 32);
            const float4* whr = (const float4*)(Whh1 + row * H_ + q * 32);
#pragma unroll
            for (int j4 = 0; j4 < 8; ++j4) {
                float4 f = wir[j4];
                w[g * 32 + j4 * 2]      = packh2(f.x, f.y);
                w[g * 32 + j4 * 2 + 1]  = packh2(f.z, f.w);
                f = whr[j4];
                w[g * 32 + 16 + j4 * 2] = packh2(f.x, f.y);
                w[g * 32 + 17 + j4 * 2] = packh2(f.z, f.w);
            }
            bias[g] = bih1[row] + bhh1[row];
        }
        const bool isret = (mb < 64);
        const int hr = isret ? mb : mb - 64;
        const float* W1 = isret ? Wr1 : Wv1;
        const float4* whr = (const float4*)(W1 + hr * H_ + q * 32);
#pragma unroll
        for (int j4 = 0; j4 < 8; ++j4) {
            const float4 f = whr[j4];
            w[128 + j4 * 2]     = packh2(f.x, f.y);
            w[128 + j4 * 2 + 1] = packh2(f.z, f.w);
        }
        hb1 = (isret ? br1 : bv1)[hr];
        hw2 = (isret ? Wr2 : Wv2)[hr];
    }

    const float* xrow = x + (size_t)b * S_ * D_;
    for (int i = tid; i < 2048; i += NT) {      // window 0 (steps 0..511)
        const float4 v = *(const float4*)(xrow + i * 4);
        xp2[0][i * 2]     = packh2(v.x, v.y);
        xp2[0][i * 2 + 1] = packh2(v.z, v.w);
    }
    if (tid < 64) {
        h1b[0][tid] = 0u; h1b[1][tid] = 0u;
        h2b[0][tid] = 0u; h2b[1][tid] = 0u;
    }
    if (tid < 16) ((float*)redbuf)[tid] = 0.f;
    float c1 = 0.f, c2 = 0.f;
    __syncthreads();

    for (int t = 0; t <= S_; ++t) {
        // prefetch next 512-step x window (uniform branch; 4 boundary iters)
        if ((t & 511) == 0 && t < S_ - 512) {
            const int nw = (t >> 9) + 1;
            u32* dst = xp2[nw & 1];
            const float* src = xrow + (size_t)nw * 8192;
            for (int i = tid; i < 2048; i += NT) {
                const float4 v = *(const float4*)(src + i * 4);
                dst[i * 2]     = packh2(v.x, v.y);
                dst[i * 2 + 1] = packh2(v.z, v.w);
            }
        }
        // stage (ret,vol) for output index t-3 (head partials written iter t-1)
        if (t >= 3 && tid == 0) {
            const float* rb = redbuf[t & 1];
            rvr[t - 3] = rb[0] + rb[1] + rb[2] + rb[3] + br2f;
            rvv[t - 3] = softplus_(rb[4] + rb[5] + rb[6] + rb[7] + bv2f);
        }

        if (isA) {
            if (t < S_) {   // ---- layer 0, step t
                float a0 = 0.f, a1 = 0.f, a2 = 0.f, a3 = 0.f;
                const uint4 xv = *(const uint4*)(&xp2[(t >> 9) & 1][(t & 511) * 8 + k0 * 4]);
                GD4(xv.x, 0) GD4(xv.y, 1) GD4(xv.z, 2) GD4(xv.w, 3)
                const uint4* h4 = (const uint4*)(&h1b[(t + 1) & 1][k0 * 32]);
#pragma unroll
                for (int p4 = 0; p4 < 8; ++p4) {
                    const uint4 v = h4[p4];
                    GD4(v.x, 4 + p4 * 4) GD4(v.y, 5 + p4 * 4)
                    GD4(v.z, 6 + p4 * 4) GD4(v.w, 7 + p4 * 4)
                }
                a0 += __shfl_xor(a0, 1); a1 += __shfl_xor(a1, 1);
                a2 += __shfl_xor(a2, 1); a3 += __shfl_xor(a3, 1);
                float h1val = 0.f;
                if (k0 == 0) {
                    const float ig = sigm(a0 + bias[0]);
                    const float fg = sigm(a1 + bias[1]);
                    const float gc = tanh_(a2 + bias[2]);
                    const float og = sigm(a3 + bias[3]);
                    c1 = fg * c1 + ig * gc;
                    h1val = og * tanh_(c1);
                }
                const float hnb = __shfl_down(h1val, 2);
                if ((tid & 3) == 0) h1b[t & 1][ma >> 1] = packh2(h1val, hnb);
                if (t == S_ - 1 && k0 == 0) {
                    out[HH0 + (size_t)b * H_ + ma] = h1val;
                    out[HC0 + (size_t)b * H_ + ma] = c1;
                }
            }
        } else {
            if (t >= 1) {   // ---- layer 1 + heads, step u = t-1
                const int u = t - 1;
                float a0 = 0.f, a1 = 0.f, a2 = 0.f, a3 = 0.f, hacc = 0.f;
                const uint4* h1v = (const uint4*)(&h1b[u & 1][q * 16]);
#pragma unroll
                for (int p4 = 0; p4 < 4; ++p4) {
                    const uint4 v = h1v[p4];
                    GD32(v.x, p4 * 4)     GD32(v.y, p4 * 4 + 1)
                    GD32(v.z, p4 * 4 + 2) GD32(v.w, p4 * 4 + 3)
                }
                const uint4* h2v = (const uint4*)(&h2b[t & 1][q * 16]);
#pragma unroll
                for (int p4 = 0; p4 < 4; ++p4) {
                    const uint4 v = h2v[p4];
                    GD32(v.x, 16 + p4 * 4) GD32(v.y, 17 + p4 * 4)
                    GD32(v.z, 18 + p4 * 4) GD32(v.w, 19 + p4 * 4)
                    hacc = fdot2(v.x, w[128 + p4 * 4], hacc);
                    hacc = fdot2(v.y, w[129 + p4 * 4], hacc);
                    hacc = fdot2(v.z, w[130 + p4 * 4], hacc);
                    hacc = fdot2(v.w, w[131 + p4 * 4], hacc);
                }
                a0 += __shfl_xor(a0, 1); a0 += __shfl_xor(a0, 2);
                a1 += __shfl_xor(a1, 1); a1 += __shfl_xor(a1, 2);
                a2 += __shfl_xor(a2, 1); a2 += __shfl_xor(a2, 2);
                a3 += __shfl_xor(a3, 1); a3 += __shfl_xor(a3, 2);
                hacc += __shfl_xor(hacc, 1); hacc += __shfl_xor(hacc, 2);
                float h2val = 0.f, pc = 0.f;
                if (q == 0) {
                    const float ig = sigm(a0 + bias[0]);
                    const float fg = sigm(a1 + bias[1]);
                    const float gc = tanh_(a2 + bias[2]);
                    const float og = sigm(a3 + bias[3]);
                    c2 = fg * c2 + ig * gc;
                    h2val = og * tanh_(c2);
                    float d = hacc + hb1;            // head on h2_{u-1}
                    d = d > 0.f ? d : 0.01f * d;     // leaky_relu(0.01)
                    pc = d * hw2;
                }
                pc += __shfl_xor(pc, 4);  pc += __shfl_xor(pc, 8);
                pc += __shfl_xor(pc, 16); pc += __shfl_xor(pc, 32);
                if ((tb & 63) == 0) redbuf[u & 1][tb >> 6] = pc;
                const float hnb = __shfl_down(h2val, 4);
                if ((tb & 7) == 0) h2b[u & 1][mb >> 1] = packh2(h2val, hnb);
                if (u == S_ - 1 && q == 0) {
                    out[HH0 + 32768 + (size_t)b * H_ + mb] = h2val;
                    out[HC0 + 32768 + (size_t)b * H_ + mb] = c2;
                }
            }
        }
        __syncthreads();
    }

    // ---- epilogue: head on h2_{S-1} (stored parity (S_-1)&1 = 1)
    if (!isA) {
        float hacc = 0.f;
        const uint4* h2v = (const uint4*)(&h2b[1][q * 16]);
#pragma unroll
        for (int p4 = 0; p4 < 4; ++p4) {
            const uint4 v = h2v[p4];
            hacc = fdot2(v.x, w[128 + p4 * 4], hacc);
            hacc = fdot2(v.y, w[129 + p4 * 4], hacc);
            hacc = fdot2(v.z, w[130 + p4 * 4], hacc);
            hacc = fdot2(v.w, w[131 + p4 * 4], hacc);
        }
        hacc += __shfl_xor(hacc, 1); hacc += __shfl_xor(hacc, 2);
        float pc = 0.f;
        if (q == 0) {
            float d = hacc + hb1;
            d = d > 0.f ? d : 0.01f * d;
            pc = d * hw2;
        }
        pc += __shfl_xor(pc, 4);  pc += __shfl_xor(pc, 8);
        pc += __shfl_xor(pc, 16); pc += __shfl_xor(pc, 32);
        if ((tb & 63) == 0) redbuf[0][tb >> 6] = pc;   // redbuf[0] is free now
    }
    __syncthreads();
    if (tid == 0) {
        const float* rb = redbuf[1];   // head(h2_{S-2}), written at iter S_
        rvr[S_ - 2] = rb[0] + rb[1] + rb[2] + rb[3] + br2f;
        rvv[S_ - 2] = softplus_(rb[4] + rb[5] + rb[6] + rb[7] + bv2f);
        const float* rc = redbuf[0];   // head(h2_{S-1}), epilogue
        rvr[S_ - 1] = rc[0] + rc[1] + rc[2] + rc[3] + br2f;
        rvv[S_ - 1] = softplus_(rc[4] + rc[5] + rc[6] + rc[7] + bv2f);
    }
    __syncthreads();
    // ---- bulk output flush (coalesced f32)
    for (int s = tid; s < S_; s += NT) {
        out[RET0 + (size_t)b * S_ + s] = rvr[s];
        out[VOL0 + (size_t)b * S_ + s] = rvv[s];
    }
}

extern "C" void kernel_launch(void* const* d_in, const int* in_sizes, int n_in,
                              void* d_out, int out_size, void* d_ws, size_t ws_size,
                              hipStream_t stream) {
    (void)in_sizes; (void)n_in; (void)out_size; (void)d_ws; (void)ws_size;
    const float* x    = (const float*)d_in[0];
    const float* Wih0 = (const float*)d_in[1];
    const float* Whh0 = (const float*)d_in[2];
    const float* bih0 = (const float*)d_in[3];
    const float* bhh0 = (const float*)d_in[4];
    const float* Wih1 = (const float*)d_in[5];
    const float* Whh1 = (const float*)d_in[6];
    const float* bih1 = (const float*)d_in[7];
    const float* bhh1 = (const float*)d_in[8];
    const float* Wr1  = (const float*)d_in[9];
    const float* br1  = (const float*)d_in[10];
    const float* Wr2  = (const float*)d_in[11];
    const float* br2  = (const float*)d_in[12];
    const float* Wv1  = (const float*)d_in[13];
    const float* bv1  = (const float*)d_in[14];
    const float* Wv2  = (const float*)d_in[15];
    const float* bv2  = (const float*)d_in[16];
    float* out = (float*)d_out;

    mtl_fused<<<B_, NT, 0, stream>>>(x, Wih0, Whh0, bih0, bhh0,
                                     Wih1, Whh1, bih1, bhh1,
                                     Wr1, br1, Wr2, br2, Wv1, bv1, Wv2, bv2, out);
}